// Round 14
// baseline (490.216 us; speedup 1.0000x reference)
//
#include <hip/hip_runtime.h>
#include <hip/hip_bf16.h>
#include <math.h>

#define HW 4096
#define TP 264   // temporal A-tile pitch in halves: 528 B row stride == 4 mod 32 banks (2-way, free)
#define CNH 4    // conv: output rows per block (rolling window)

typedef __attribute__((ext_vector_type(8))) short bf16x8;
typedef _Float16 f16x8 __attribute__((ext_vector_type(8)));
typedef __attribute__((ext_vector_type(4))) float f32x4;

#define MFMA_BF16(a, b, c) __builtin_amdgcn_mfma_f32_16x16x32_bf16((a), (b), (c), 0, 0, 0)
#define MFMA_F16(a, b, c)  __builtin_amdgcn_mfma_f32_16x16x32_f16((a), (b), (c), 0, 0, 0)

static __device__ __forceinline__ float gelu_f(float xv) {
    // tanh-gelu via sigmoid identity: 0.5x(1+tanh(t)) = x*e/(e+1), e=exp(2t)
    float x2 = xv*xv;
    float t2 = xv*(1.5957691216057308f + 0.07135481627260025f*x2);
    float ee = __expf(t2);
    return xv*(1.f - __builtin_amdgcn_rcpf(ee + 1.f));
}

// ---------------- Prep: fp32 [nmat][128][128] -> bf16 [nmat][128][128] transposed ----------------
__global__ __launch_bounds__(256) void k_prep_t(
    const float* __restrict__ src, __hip_bfloat16* __restrict__ dst)
{
    __shared__ float t[32*33];
    int m  = blockIdx.x;
    int tr = blockIdx.y >> 2, tc = blockIdx.y & 3;
    int tid = threadIdx.x;
    for (int l = tid; l < 1024; l += 256) {
        int r = l >> 5, c = l & 31;
        t[r*33 + c] = src[m*16384 + (tr*32 + r)*128 + (tc*32 + c)];
    }
    __syncthreads();
    for (int l = tid; l < 1024; l += 256) {
        int c = l >> 5, r = l & 31;
        dst[m*16384 + (tc*32 + c)*128 + (tr*32 + r)] = __float2bfloat16(t[r*33 + c]);
    }
}

// ---------------- Prep: temporal tables + router weight tile ----------------
__global__ __launch_bounds__(256) void k_prep_enc(
    const float* __restrict__ encr, const float* __restrict__ enci,
    const float* __restrict__ decr, const float* __restrict__ deci,
    const float* __restrict__ dt,
    const float* __restrict__ lamr, const float* __restrict__ lami,
    const float* __restrict__ rw,
    _Float16* __restrict__ Benc, _Float16* __restrict__ BdecX,
    float4* __restrict__ coefG, float* __restrict__ nscG,
    __hip_bfloat16* __restrict__ rwB)
{
    int idx = blockIdx.x*256 + threadIdx.x;
    if (idx < 16384) {
        int n = idx >> 7, k = idx & 127;
        int e = n & 63, d = k & 63;
        float v;
        if (n < 64) v = (k < 64) ? encr[d*64 + e] : -enci[d*64 + e];
        else        v = (k < 64) ? enci[d*64 + e] :  encr[d*64 + e];
        Benc[idx] = (_Float16)v;
    }
    if (idx < 16384) {
        int n = idx >> 8, k = idx & 255;
        int kk = k & 127;
        int e = kk & 63;
        float v = (kk < 64) ? decr[e*64 + n] : -deci[e*64 + n];
        BdecX[idx] = (_Float16)v;
    }
    if (idx < 2048) {
        int bt = idx >> 6, e = idx & 63;
        float dtv = dt[bt];
        float lr = lamr[e];
        float sp = (lr > 20.f) ? lr : log1pf(expf(lr));
        float lre = -sp, lim = lami[e];
        float inv = 1.f / (lre*lre + lim*lim);
        float ex = expf(lre*dtv);
        float sn, cs; sincosf(lim*dtv, &sn, &cs);
        float ar = ex*cs, ai = ex*sn;
        float fr = ((ar - 1.f)*lre + ai*lim)*inv;
        float fi = (ai*lre - (ar - 1.f)*lim)*inv;
        coefG[idx] = make_float4(ar, ai, fr, fi);
    }
    if (idx < 2048) {
        int n = idx >> 7, k = idx & 127;
        float v = (n < 4) ? rw[k*4 + n] : 0.f;
        rwB[idx] = __float2bfloat16(v);
    }
    if (idx < 32) nscG[idx] = 0.01f * sqrtf(dt[idx]);
}

// ---------------- Stage 1 (FUSED, rolling window): LN + 3x3 conv MFMA + residual ----------------
// Block owns CNH=4 consecutive output rows. A 3-slot LDS ring (slot = gh mod 3) holds LN'd
// input rows. Per output row: LN exactly ONE new row (32 loads, 3 barriers) instead of 3 rows
// (96 loads, 6 barriers); the next row's global loads are issued BEFORE the 288-MFMA phase so
// HBM/L3 latency hides under compute (T14 async-split). x logical reads drop 3x -> 1.5x.
// LDS rows pitch-128 halves with XOR swizzle off^((R&7)<<3) on all 16B accesses (verified R11/12).
__global__ __launch_bounds__(256) void k_conv_mfma(
    const float* __restrict__ xr, const float* __restrict__ xi,
    const float* __restrict__ lw, const float* __restrict__ lb,
    const __hip_bfloat16* __restrict__ wB,
    const float* __restrict__ cb,
    float* __restrict__ x1)
{
    __shared__ __align__(16) short ring[3*66*128];   // 50688 B
    __shared__ float ps[256];
    __shared__ float ps2[256];
    __shared__ float mu_s[64];
    __shared__ float rs_s[64];
    __shared__ float lwS[128];
    __shared__ float lbS[128];
    int bt = blockIdx.x, h0 = blockIdx.y * CNH;
    int tid = threadIdx.x;
    int wl = tid & 63;   // pixel lane (W index)
    int q  = tid >> 6;   // wave id = channel block [32q, 32q+32)

    if (tid < 128) { lwS[tid] = lw[tid]; lbS[tid] = lb[tid]; }
    if (tid >= 128 && tid < 224) {   // zero px=0 / px=65 pad columns of all 3 slots (stay zero)
        int t = tid - 128;
        int sl = t >> 5, t2 = t & 31;
        int px = (t2 & 1) ? 65 : 0;
        int j = t2 >> 1;
        int R = sl*66 + px;
        *(float4*)&ring[R*128 + ((j*8) ^ ((R & 7) << 3))] = make_float4(0.f,0.f,0.f,0.f);
    }
    // lwS/pads become visible via the barriers inside the first finrow call.

    const float* srcb = (q < 2) ? xr : xi;
    int dbase = (q & 1) * 32;
    float v[32];
    float sS = 0.f, s2S = 0.f;

    // issue 32 coalesced loads for global row gh; accumulate per-lane partial stats
    auto loadrow = [&](int gh) {
        if ((unsigned)gh < 64u) {
            const float* base = &srcb[((size_t)(bt*64 + dbase))*HW + gh*64 + wl];
            float s = 0.f, s2 = 0.f;
            #pragma unroll
            for (int k = 0; k < 32; k++) {
                float vv = base[(size_t)k*HW];
                v[k] = vv; s += vv; s2 += vv*vv;
            }
            sS = s; s2S = s2;
        }
    };
    // stats reduce + LN pack of the previously loaded row into ring slot gh%3 (3 barriers)
    auto finrow = [&](int gh) {
        bool ok = ((unsigned)gh < 64u);   // block-uniform
        if (ok) { ps[wl*4 + q] = sS; ps2[wl*4 + q] = s2S; }
        __syncthreads();
        if (ok && tid < 64) {
            float ss = ps[tid*4+0]+ps[tid*4+1]+ps[tid*4+2]+ps[tid*4+3];
            float qq = ps2[tid*4+0]+ps2[tid*4+1]+ps2[tid*4+2]+ps2[tid*4+3];
            float mu = ss * 0.0078125f;
            float var = qq * 0.0078125f - mu*mu;
            mu_s[tid] = mu;
            rs_s[tid] = rsqrtf(var + 1e-5f);
        }
        __syncthreads();
        int sl = ((gh % 3) + 3) % 3;
        int R = sl*66 + wl + 1;
        int key = (R & 7) << 3;
        short* drow = &ring[R*128];
        if (ok) {
            float mu = mu_s[wl], rs = rs_s[wl];
            #pragma unroll
            for (int j = 0; j < 4; j++) {
                union { __hip_bfloat16 hh[8]; float4 f; } u;
                #pragma unroll
                for (int k = 0; k < 8; k++) {
                    int c = q*32 + j*8 + k;
                    u.hh[k] = __float2bfloat16((v[j*8+k] - mu)*rs*lwS[c] + lbS[c]);
                }
                *(float4*)&drow[(q*32 + j*8) ^ key] = u.f;
            }
        } else {
            float4 z = make_float4(0.f,0.f,0.f,0.f);
            #pragma unroll
            for (int j = 0; j < 4; j++) *(float4*)&drow[(q*32 + j*8) ^ key] = z;
        }
        __syncthreads();   // pack published before MFMA reads
    };

    // prologue: rows h0-1 and h0
    loadrow(h0 - 1); finrow(h0 - 1);
    loadrow(h0);     finrow(h0);
    loadrow(h0 + 1);

    int wv = tid >> 6, l = tid & 63, lm = l & 15, qq2 = l >> 4;
    int n0 = wv * 32;

    #pragma unroll
    for (int hh = 0; hh < CNH; hh++) {
        int h = h0 + hh;
        finrow(h + 1);                       // consumes v (row h+1) -> ring slot (h+1)%3
        if (hh < CNH - 1) loadrow(h + 2);    // issue next-row loads BEFORE the MFMA phase

        f32x4 acc[4][2];
        #pragma unroll
        for (int mi = 0; mi < 4; mi++)
            #pragma unroll
            for (int ni = 0; ni < 2; ni++)
                acc[mi][ni] = (f32x4){0.f,0.f,0.f,0.f};

        for (int p = 0; p < 9; p++) {
            int kh = p / 3, kw = p - kh*3;
            const __hip_bfloat16* wp = wB + p*16384;
            int sl = ((h - 1 + kh) % 3 + 3) % 3;
            int rb = sl*66 + kw;
            #pragma unroll
            for (int ks = 0; ks < 4; ks++) {
                int ko = ks*32 + qq2*8;
                bf16x8 b0 = *(const bf16x8*)(wp + (n0 + lm)*128 + ko);
                bf16x8 b1 = *(const bf16x8*)(wp + (n0 + 16 + lm)*128 + ko);
                #pragma unroll
                for (int mi = 0; mi < 4; mi++) {
                    int R = rb + mi*16 + lm;
                    bf16x8 a = *(const bf16x8*)&ring[R*128 + (ko ^ ((R & 7) << 3))];
                    acc[mi][0] = MFMA_BF16(a, b0, acc[mi][0]);
                    acc[mi][1] = MFMA_BF16(a, b1, acc[mi][1]);
                }
            }
        }
        #pragma unroll
        for (int ni = 0; ni < 2; ni++) {
            int oc = n0 + ni*16 + lm;
            float bias = cb[oc];
            const float* rsp = (oc < 64) ? xr : xi;
            const float* rbase = &rsp[(bt*64 + (oc & 63))*HW + h*64];
            #pragma unroll
            for (int mi = 0; mi < 4; mi++) {
                #pragma unroll
                for (int r = 0; r < 4; r++) {
                    int w = mi*16 + qq2*4 + r;
                    x1[(size_t)(bt*HW + h*64 + w)*128 + oc] = acc[mi][ni][r] + bias + rbase[w];
                }
            }
        }
        // MFMA/epilogue reads of this iter complete before next finrow's first barrier,
        // so next iter's pack (slot (h+2)%3 == slot of row h-1) is safe without extra fences.
    }
}

// ---------------- Stage 2: temporal via MFMA, f16 + hi/lo-split decode ----------------
// block = 128 thr / 2 waves, 4 pixels. A-tile 64 rows = (n_local,t), pitch 264:
// cols 0..127 = z then h_hi [re|im]; cols 128..255 = h_lo [re|im].
// GEMM1 (encode, K=128) -> in-fragment complex scan -> h hi/lo to tile -> GEMM2 (decode, K=256).
__global__ __launch_bounds__(128) void k_temporal_mfma(
    float* xio,
    const float* __restrict__ lw, const float* __restrict__ lb,
    const float* __restrict__ sbr, const float* __restrict__ sbi,
    const _Float16* __restrict__ Benc, const _Float16* __restrict__ BdecX,
    const float4* __restrict__ coefG, const float* __restrict__ nscG,
    const float* __restrict__ nzr, const float* __restrict__ nzi)
{
    __shared__ __align__(16) short At[64*TP];   // 33792 B
    int n0  = blockIdx.x * 4;
    int b   = n0 >> 12;
    int hw0 = n0 & 4095;
    int tid = threadIdx.x;

    // LN: 2 threads per row (row = n_local*16 + t), f16 into A-tile cols 0..127
    {
        int row = tid >> 1, half = tid & 1;
        int nl = row >> 4, t = row & 15;
        const float4* src = (const float4*)&xio[((size_t)((b*16 + t)*HW) + hw0 + nl)*128 + half*64];
        float4 v[16];
        float s = 0.f, s2 = 0.f;
        #pragma unroll
        for (int j = 0; j < 16; j++) {
            v[j] = src[j];
            s  += v[j].x + v[j].y + v[j].z + v[j].w;
            s2 += v[j].x*v[j].x + v[j].y*v[j].y + v[j].z*v[j].z + v[j].w*v[j].w;
        }
        s  += __shfl_xor(s, 1, 64);
        s2 += __shfl_xor(s2, 1, 64);
        float mu  = s * 0.0078125f;
        float var = s2 * 0.0078125f - mu*mu;
        float rsq = rsqrtf(var + 1e-5f);
        const float4* lw4 = (const float4*)(lw + half*64);
        const float4* lb4 = (const float4*)(lb + half*64);
        short* dstrow = &At[row*TP + half*64];
        #pragma unroll
        for (int j = 0; j < 16; j++) {
            float4 wv4 = lw4[j], bv = lb4[j];
            union { _Float16 h[4]; float2 f; } u;
            u.h[0] = (_Float16)((v[j].x - mu)*rsq*wv4.x + bv.x);
            u.h[1] = (_Float16)((v[j].y - mu)*rsq*wv4.y + bv.y);
            u.h[2] = (_Float16)((v[j].z - mu)*rsq*wv4.z + bv.z);
            u.h[3] = (_Float16)((v[j].w - mu)*rsq*wv4.w + bv.w);
            *(float2*)(dstrow + j*4) = u.f;
        }
    }
    __syncthreads();   // coef/LN cross-wave publish; tile rows are wave-private below

    int wv = tid >> 6, l = tid & 63, lm = l & 15, q = l >> 4;

    // GEMM1: u_pre = z @ Benc  (ni<4 = re cols, ni+4 = im cols)
    f32x4 acc[2][8];
    #pragma unroll
    for (int mi = 0; mi < 2; mi++)
        #pragma unroll
        for (int ni = 0; ni < 8; ni++)
            acc[mi][ni] = (f32x4){0.f,0.f,0.f,0.f};
    #pragma unroll
    for (int ks = 0; ks < 4; ks++) {
        int ko = ks*32 + q*8;
        f16x8 a0 = *(const f16x8*)&At[((2*wv+0)*16 + lm)*TP + ko];
        f16x8 a1 = *(const f16x8*)&At[((2*wv+1)*16 + lm)*TP + ko];
        #pragma unroll
        for (int ni = 0; ni < 8; ni++) {
            f16x8 bb = *(const f16x8*)(Benc + (ni*16 + lm)*128 + ko);
            acc[0][ni] = MFMA_F16(a0, bb, acc[0][ni]);
            acc[1][ni] = MFMA_F16(a1, bb, acc[1][ni]);
        }
    }

    // in-fragment complex scan (coef from global table); write h hi/lo into wave rows
    int btbase = b*16;
    #pragma unroll
    for (int ni = 0; ni < 4; ni++) {
        int e = ni*16 + lm;
        float br = sbr[e], bi = sbi[e];
        float4 cf[4]; float ns[4];
        #pragma unroll
        for (int r = 0; r < 4; r++) {
            int t = q*4 + r;
            cf[r] = coefG[(btbase + t)*64 + e];
            ns[r] = nscG[btbase + t];
        }
        #pragma unroll
        for (int mi = 0; mi < 2; mi++) {
            int nl = 2*wv + mi;
            int ng = n0 + nl;
            float nrv[4], niv[4];
            #pragma unroll
            for (int r = 0; r < 4; r++) {
                int off = (ng*16 + q*4 + r)*64 + e;
                nrv[r] = nzr[off];
                niv[r] = nzi[off];
            }
            float hr = 0.f, hi = 0.f, Apr = 1.f, Api = 0.f;
            float hrs[4], his[4], Aprs[4], Apis[4];
            #pragma unroll
            for (int r = 0; r < 4; r++) {
                float Sr = acc[mi][ni][r] + br;
                float Si = acc[mi][ni+4][r] + bi;
                float ur = Sr*cf[r].z - Si*cf[r].w + ns[r]*nrv[r];
                float ui = Sr*cf[r].w + Si*cf[r].z + ns[r]*niv[r];
                if (r == 0) { hr = ur; hi = ui; Apr = cf[0].x; Api = cf[0].y; }
                else {
                    float tr = cf[r].x*hr - cf[r].y*hi + ur;
                    float ti = cf[r].x*hi + cf[r].y*hr + ui;
                    hr = tr; hi = ti;
                    tr = cf[r].x*Apr - cf[r].y*Api;
                    ti = cf[r].x*Api + cf[r].y*Apr;
                    Apr = tr; Api = ti;
                }
                hrs[r] = hr; his[r] = hi; Aprs[r] = Apr; Apis[r] = Api;
            }
            // quad-prefix over segments (A,H): h_out = H + A*h_in
            float Ar = Apr, Ai = Api, Hr = hr, Hi = hi;
            #pragma unroll
            for (int off = 16; off <= 32; off <<= 1) {
                float pAr = __shfl_up(Ar, off, 64);
                float pAi = __shfl_up(Ai, off, 64);
                float pHr = __shfl_up(Hr, off, 64);
                float pHi = __shfl_up(Hi, off, 64);
                if (l >= off) {
                    Hr = Hr + Ar*pHr - Ai*pHi;
                    Hi = Hi + Ar*pHi + Ai*pHr;
                    float tAr = Ar*pAr - Ai*pAi;
                    float tAi = Ar*pAi + Ai*pAr;
                    Ar = tAr; Ai = tAi;
                }
            }
            float gr = __shfl_up(Hr, 16, 64);
            float gi = __shfl_up(Hi, 16, 64);
            if (q == 0) { gr = 0.f; gi = 0.f; }
            #pragma unroll
            for (int r = 0; r < 4; r++) {
                float fhr = hrs[r] + Aprs[r]*gr - Apis[r]*gi;
                float fhi = his[r] + Aprs[r]*gi + Apis[r]*gr;
                int row = nl*16 + q*4 + r;
                _Float16 hrh = (_Float16)fhr;
                _Float16 hih = (_Float16)fhi;
                *(_Float16*)&At[row*TP + e]        = hrh;
                *(_Float16*)&At[row*TP + 64 + e]   = hih;
                *(_Float16*)&At[row*TP + 128 + e]  = (_Float16)(fhr - (float)hrh);
                *(_Float16*)&At[row*TP + 192 + e]  = (_Float16)(fhi - (float)hih);
            }
        }
    }

    // GEMM2: drift = (h_hi + h_lo) @ BdecX  (K=256, duplicated weights)
    f32x4 acc2[2][4];
    #pragma unroll
    for (int mi = 0; mi < 2; mi++)
        #pragma unroll
        for (int ni = 0; ni < 4; ni++)
            acc2[mi][ni] = (f32x4){0.f,0.f,0.f,0.f};
    #pragma unroll
    for (int ks = 0; ks < 8; ks++) {
        int ko = ks*32 + q*8;
        f16x8 a0 = *(const f16x8*)&At[((2*wv+0)*16 + lm)*TP + ko];
        f16x8 a1 = *(const f16x8*)&At[((2*wv+1)*16 + lm)*TP + ko];
        #pragma unroll
        for (int ni = 0; ni < 4; ni++) {
            f16x8 bb = *(const f16x8*)(BdecX + (ni*16 + lm)*256 + ko);
            acc2[0][ni] = MFMA_F16(a0, bb, acc2[0][ni]);
            acc2[1][ni] = MFMA_F16(a1, bb, acc2[1][ni]);
        }
    }

    // epilogue: xio.re += drift (in place, re-half only)
    #pragma unroll
    for (int mi = 0; mi < 2; mi++) {
        int nl = 2*wv + mi;
        #pragma unroll
        for (int ni = 0; ni < 4; ni++) {
            int d = ni*16 + lm;
            #pragma unroll
            for (int r = 0; r < 4; r++) {
                int t = q*4 + r;
                size_t idx = ((size_t)((b*16 + t)*HW) + hw0 + nl)*128 + d;
                xio[idx] = xio[idx] + acc2[mi][ni][r];
            }
        }
    }
}

// ---------------- Stage 3: MoE FFN via MFMA (measured-best 114 us structure) ----
// 256 thr / 64 tokens / 35.8 KB LDS. Column-split: wave owns a 32-col weight strip.
__global__ __launch_bounds__(256) void k_moe_mfma(
    const float* __restrict__ xio,
    float* __restrict__ outp,
    const __hip_bfloat16* __restrict__ rwB, const float* __restrict__ rb,
    const __hip_bfloat16* __restrict__ w1b, const float* __restrict__ b1,
    const __hip_bfloat16* __restrict__ w2b, const float* __restrict__ b2)
{
    __shared__ __align__(16) short smem[2*64*136];   // tokA | hidA; reused as fp32 tile 64x129
    __shared__ float gates[256];
    short* tokA = smem;
    short* hidA = smem + 64*136;
    float* tile = (float*)smem;
    int tok0 = blockIdx.x * 64;
    int tid = threadIdx.x;
    for (int lsd = tid; lsd < 2048; lsd += 256) {
        int t = lsd >> 5, j = lsd & 31;
        float4 v = *(const float4*)&xio[(size_t)(tok0 + t)*128 + j*4];
        union { __hip_bfloat16 h[4]; float2 f; } u;
        u.h[0] = __float2bfloat16(v.x);
        u.h[1] = __float2bfloat16(v.y);
        u.h[2] = __float2bfloat16(v.z);
        u.h[3] = __float2bfloat16(v.w);
        *(float2*)&tokA[t*136 + j*4] = u.f;
    }
    __syncthreads();

    int wv = tid >> 6, l = tid & 63, lm = l & 15, q = l >> 4;
    int n0 = wv * 32;

    // Router via MFMA: wave wv computes logits for token rows [n0, n0+32).
    // gates published to other waves by the post-GELU barrier of expert 0.
    {
        f32x4 racc[2];
        racc[0] = (f32x4){0.f,0.f,0.f,0.f};
        racc[1] = (f32x4){0.f,0.f,0.f,0.f};
        #pragma unroll
        for (int ks = 0; ks < 4; ks++) {
            int ko = ks*32 + q*8;
            bf16x8 bb = *(const bf16x8*)(rwB + lm*128 + ko);
            bf16x8 a0 = *(const bf16x8*)&tokA[(n0 + lm)*136 + ko];
            bf16x8 a1 = *(const bf16x8*)&tokA[(n0 + 16 + lm)*136 + ko];
            racc[0] = MFMA_BF16(a0, bb, racc[0]);
            racc[1] = MFMA_BF16(a1, bb, racc[1]);
        }
        float rb_l = rb[lm & 3];
        #pragma unroll
        for (int mi = 0; mi < 2; mi++) {
            #pragma unroll
            for (int r = 0; r < 4; r++) {
                float g = racc[mi][r] + rb_l;
                float mx = fmaxf(g, __shfl_xor(g, 1, 64));
                mx = fmaxf(mx, __shfl_xor(mx, 2, 64));
                float ev = __expf(g - mx);
                float sv = ev + __shfl_xor(ev, 1, 64);
                sv += __shfl_xor(sv, 2, 64);
                if (lm < 4)
                    gates[(n0 + mi*16 + q*4 + r)*4 + lm] = ev * __builtin_amdgcn_rcpf(sv);
            }
        }
    }

    f32x4 outa[4][2];
    #pragma unroll
    for (int mi = 0; mi < 4; mi++)
        #pragma unroll
        for (int ni = 0; ni < 2; ni++)
            outa[mi][ni] = (f32x4){0.f,0.f,0.f,0.f};

    for (int e = 0; e < 4; e++) {
        // GEMM1: hid[all 64 rows][n0..n0+32) = tok @ w1[e] strip  (reads tokA only)
        f32x4 acc1[4][2];
        #pragma unroll
        for (int mi = 0; mi < 4; mi++)
            #pragma unroll
            for (int ni = 0; ni < 2; ni++)
                acc1[mi][ni] = (f32x4){0.f,0.f,0.f,0.f};
        const __hip_bfloat16* wp1 = w1b + e*16384;
        #pragma unroll
        for (int ks = 0; ks < 4; ks++) {
            int ko = ks*32 + q*8;
            bf16x8 b0  = *(const bf16x8*)(wp1 + (n0 + lm)*128 + ko);
            bf16x8 b1v = *(const bf16x8*)(wp1 + (n0 + 16 + lm)*128 + ko);
            #pragma unroll
            for (int mi = 0; mi < 4; mi++) {
                bf16x8 a = *(const bf16x8*)&tokA[(mi*16 + lm)*136 + ko];
                acc1[mi][0] = MFMA_BF16(a, b0,  acc1[mi][0]);
                acc1[mi][1] = MFMA_BF16(a, b1v, acc1[mi][1]);
            }
        }
        // GELU -> hidA own cols (writes fenced vs GEMM2(e-1) by loop-end barrier)
        #pragma unroll
        for (int ni = 0; ni < 2; ni++) {
            int hcol = n0 + ni*16 + lm;
            float bb = b1[e*128 + hcol];
            #pragma unroll
            for (int mi = 0; mi < 4; mi++) {
                #pragma unroll
                for (int r = 0; r < 4; r++) {
                    float hv = gelu_f(acc1[mi][ni][r] + bb);
                    int m = mi*16 + q*4 + r;
                    *(__hip_bfloat16*)&hidA[m*136 + hcol] = __float2bfloat16(hv);
                }
            }
        }
        __syncthreads();   // publish hidA (and gates on e=0)
        // GEMM2: delta[all rows][n0..n0+32) = hid @ w2[e] strip (contracts all 128 h-cols)
        f32x4 acc2[4][2];
        #pragma unroll
        for (int mi = 0; mi < 4; mi++)
            #pragma unroll
            for (int ni = 0; ni < 2; ni++)
                acc2[mi][ni] = (f32x4){0.f,0.f,0.f,0.f};
        const __hip_bfloat16* wp2 = w2b + e*16384;
        #pragma unroll
        for (int ks = 0; ks < 4; ks++) {
            int ko = ks*32 + q*8;
            bf16x8 b0  = *(const bf16x8*)(wp2 + (n0 + lm)*128 + ko);
            bf16x8 b1v = *(const bf16x8*)(wp2 + (n0 + 16 + lm)*128 + ko);
            #pragma unroll
            for (int mi = 0; mi < 4; mi++) {
                bf16x8 a = *(const bf16x8*)&hidA[(mi*16 + lm)*136 + ko];
                acc2[mi][0] = MFMA_BF16(a, b0,  acc2[mi][0]);
                acc2[mi][1] = MFMA_BF16(a, b1v, acc2[mi][1]);
            }
        }
        #pragma unroll
        for (int ni = 0; ni < 2; ni++) {
            int ocol = n0 + ni*16 + lm;
            float bb = b2[e*128 + ocol];
            #pragma unroll
            for (int mi = 0; mi < 4; mi++) {
                #pragma unroll
                for (int r = 0; r < 4; r++) {
                    int m = mi*16 + q*4 + r;
                    float g = gates[m*4 + e];
                    outa[mi][ni][r] += g * (acc2[mi][ni][r] + bb);
                }
            }
        }
        __syncthreads();   // hidA readers done before next expert's GELU overwrites
    }

    // final = residual + delta -> LDS tile (pitch 129) -> native-layout store
    #pragma unroll
    for (int ni = 0; ni < 2; ni++) {
        int col = n0 + ni*16 + lm;
        #pragma unroll
        for (int mi = 0; mi < 4; mi++) {
            #pragma unroll
            for (int r = 0; r < 4; r++) {
                int m = mi*16 + q*4 + r;
                tile[m*129 + col] = xio[(size_t)(tok0 + m)*128 + col] + outa[mi][ni][r];
            }
        }
    }
    __syncthreads();
    int bt = tok0 >> 12;
    int hw0 = tok0 & 4095;
    for (int lid = tid; lid < 8192; lid += 256) {
        int c = lid >> 6, m = lid & 63;
        int p = c >> 6, d = c & 63;
        outp[((size_t)((p*32 + bt)*64 + d))*HW + hw0 + m] = tile[m*129 + c];
    }
}

extern "C" void kernel_launch(void* const* d_in, const int* in_sizes, int n_in,
                              void* d_out, int out_size, void* d_ws, size_t ws_size,
                              hipStream_t stream)
{
    const float* x_real = (const float*)d_in[0];
    const float* x_imag = (const float*)d_in[1];
    const float* dt     = (const float*)d_in[2];
    const float* nzr    = (const float*)d_in[3];
    const float* nzi    = (const float*)d_in[4];
    const float* ln_s_w = (const float*)d_in[5];
    const float* ln_s_b = (const float*)d_in[6];
    const float* conv_w = (const float*)d_in[7];
    const float* conv_b = (const float*)d_in[8];
    const float* ln_t_w = (const float*)d_in[9];
    const float* ln_t_b = (const float*)d_in[10];
    const float* lam_re = (const float*)d_in[11];
    const float* lam_im = (const float*)d_in[12];
    const float* sbr    = (const float*)d_in[13];
    const float* sbi    = (const float*)d_in[14];
    const float* enc_re = (const float*)d_in[15];
    const float* enc_im = (const float*)d_in[16];
    const float* dec_re = (const float*)d_in[17];
    const float* dec_im = (const float*)d_in[18];
    const float* rw     = (const float*)d_in[19];
    const float* rb     = (const float*)d_in[20];
    const float* w1     = (const float*)d_in[21];
    const float* b1     = (const float*)d_in[22];
    const float* w2     = (const float*)d_in[23];
    const float* b2     = (const float*)d_in[24];

    char* ws = (char*)d_ws;
    float* bufA = (float*)ws;                                              // 64 MiB fp32 layout-A
    __hip_bfloat16* wBc  = (__hip_bfloat16*)(ws + (size_t)96*1024*1024);   // conv weights [9][oc][ic]
    __hip_bfloat16* w1b  = wBc + 9*16384;
    __hip_bfloat16* w2b  = w1b + 4*16384;
    _Float16* Benc  = (_Float16*)(w2b + 4*16384);                          // [128][128] f16
    _Float16* BdecX = Benc + 16384;                                        // [64][256] f16
    float4* coefG = (float4*)(BdecX + 16384);                              // [2048]
    float* nscG   = (float*)(coefG + 2048);                                // [32]
    __hip_bfloat16* rwB = (__hip_bfloat16*)(nscG + 32);                    // [16][128] bf16 router
    float* outp = (float*)d_out;

    k_prep_t  <<<dim3(9,16), 256, 0, stream>>>(conv_w, wBc);
    k_prep_t  <<<dim3(4,16), 256, 0, stream>>>(w1, w1b);
    k_prep_t  <<<dim3(4,16), 256, 0, stream>>>(w2, w2b);
    k_prep_enc<<<64,         256, 0, stream>>>(enc_re, enc_im, dec_re, dec_im,
                                               dt, lam_re, lam_im, rw,
                                               Benc, BdecX, coefG, nscG, rwB);

    k_conv_mfma    <<<dim3(32, 64/CNH), 256, 0, stream>>>(x_real, x_imag, ln_s_w, ln_s_b,
                                                          wBc, conv_b, bufA);
    k_temporal_mfma<<<2048,             128, 0, stream>>>(bufA, ln_t_w, ln_t_b, sbr, sbi,
                                                          Benc, BdecX, coefG, nscG, nzr, nzi);
    k_moe_mfma     <<<2048,             256, 0, stream>>>(bufA, outp, rwB, rb, w1b, b1, w2b, b2);
}